// Round 8
// baseline (61.875 us; speedup 1.0000x reference)
//
#include <hip/hip_runtime.h>
#include <hip/hip_bf16.h>

#define N_NODES 100000
#define N_EDGES 1600000
#define D_FEAT  64

// d_ws layout: [offsets (N_NODES+1) ints, padded to 1KB] [bf16 feature table]
#define OFF_WS_BYTES   ((((N_NODES + 1) * 4) + 1023) & ~1023)
#define BF16_WS_BYTES  ((size_t)N_NODES * D_FEAT * 2)
#define OFFSET_BLOCKS  ((N_NODES + 1 + 255) / 256)
#define CONVERT_BLOCKS 2048

// Fused prep (proven r5-r7): blocks [0, OFFSET_BLOCKS) binary-search offsets;
// blocks [OFFSET_BLOCKS, +CONVERT_BLOCKS) convert f32 -> bf16 (RNE) table.
__global__ __launch_bounds__(256) void prep_kernel(
        const float* __restrict__ feat,
        const int* __restrict__ seg_ids,
        int* __restrict__ offsets,
        ushort* __restrict__ fb) {
    int b = blockIdx.x;
    if (b < OFFSET_BLOCKS) {
        int n = b * 256 + threadIdx.x;
        if (n > N_NODES) return;
        int lo = 0, hi = N_EDGES;
        while (lo < hi) {
            int mid = (lo + hi) >> 1;
            if (seg_ids[mid] < n) lo = mid + 1; else hi = mid;
        }
        offsets[n] = lo;
    } else {
        const int total = N_NODES * D_FEAT / 4;
        int tid = (b - OFFSET_BLOCKS) * 256 + threadIdx.x;
        for (int i = tid; i < total; i += CONVERT_BLOCKS * 256) {
            float4 v = reinterpret_cast<const float4*>(feat)[i];
            uint ux = __float_as_uint(v.x), uy = __float_as_uint(v.y);
            uint uz = __float_as_uint(v.z), uw = __float_as_uint(v.w);
            ushort4 o;
            o.x = (ushort)((ux + 0x7fffu + ((ux >> 16) & 1u)) >> 16);
            o.y = (ushort)((uy + 0x7fffu + ((uy >> 16) & 1u)) >> 16);
            o.z = (ushort)((uz + 0x7fffu + ((uz >> 16) & 1u)) >> 16);
            o.w = (ushort)((uw + 0x7fffu + ((uw >> 16) & 1u)) >> 16);
            reinterpret_cast<ushort4*>(fb)[i] = o;
        }
    }
}

__device__ __forceinline__ void unpack8(uint4 u, float* f) {
    f[0] = __uint_as_float(u.x << 16);
    f[1] = __uint_as_float(u.x & 0xFFFF0000u);
    f[2] = __uint_as_float(u.y << 16);
    f[3] = __uint_as_float(u.y & 0xFFFF0000u);
    f[4] = __uint_as_float(u.z << 16);
    f[5] = __uint_as_float(u.z & 0xFFFF0000u);
    f[6] = __uint_as_float(u.w << 16);
    f[7] = __uint_as_float(u.w & 0xFFFF0000u);
}

// Aggregate (bf16, uint4 gathers, MLP 4): wave-per-node.
//   slot = lane>>3 (0..7): edge slot; ch = lane&7: 16B uint4 chunk of the
//   128B row. Indices staged wave-wide then distributed via __shfl.
//   Unroll 4 over slot groups -> 4 independent row-gathers in flight per lane
//   (32 edges per iter). Tail: clamped index (duplicate line, cheap) +
//   0/1-mask FMA. Reduce shfl_xor(8,16,32); lanes 0-7 store 32B each.
// Disjoint writes, no atomics -> deterministic across replays.
__global__ __launch_bounds__(256) void aggregate_bf16_kernel(
        const ushort* __restrict__ fb,
        const int* __restrict__ neigh_idx,
        const int* __restrict__ offsets,
        float* __restrict__ out) {
    int node = blockIdx.x * 4 + (threadIdx.x >> 6);   // wave-uniform
    if (node >= N_NODES) return;
    int lane = threadIdx.x & 63;
    int slot = lane >> 3;
    int ch   = lane & 7;

    int s = offsets[node];
    int e = offsets[node + 1];

    float a0[8], a1[8], a2[8], a3[8];
    #pragma unroll
    for (int k = 0; k < 8; ++k) { a0[k] = 0.f; a1[k] = 0.f; a2[k] = 0.f; a3[k] = 0.f; }

    for (int cb = s; cb < e; cb += 64) {           // 64-edge chunks (usually 1)
        int li = cb + lane;
        int ci = (li < e) ? li : (e - 1);          // loop entered => e-1 >= s
        int my_idx = neigh_idx[ci];                // 1 coalesced load / chunk
        int lim = e - cb; if (lim > 64) lim = 64;

        for (int p = 0; p < lim; p += 32) {        // 32 edges, 4 gathers in flight
            int p0 = p + slot, p1 = p0 + 8, p2 = p0 + 16, p3 = p0 + 24;
            int q0 = (p0 < lim) ? p0 : (lim - 1);
            int q1 = (p1 < lim) ? p1 : (lim - 1);
            int q2 = (p2 < lim) ? p2 : (lim - 1);
            int q3 = (p3 < lim) ? p3 : (lim - 1);
            float m0 = (p0 < lim) ? 1.f : 0.f;
            float m1 = (p1 < lim) ? 1.f : 0.f;
            float m2 = (p2 < lim) ? 1.f : 0.f;
            float m3 = (p3 < lim) ? 1.f : 0.f;
            int n0 = __shfl(my_idx, q0);
            int n1 = __shfl(my_idx, q1);
            int n2 = __shfl(my_idx, q2);
            int n3 = __shfl(my_idx, q3);
            const uint4* tb = reinterpret_cast<const uint4*>(fb);
            uint4 w0 = tb[(size_t)n0 * 8 + ch];
            uint4 w1 = tb[(size_t)n1 * 8 + ch];
            uint4 w2 = tb[(size_t)n2 * 8 + ch];
            uint4 w3 = tb[(size_t)n3 * 8 + ch];
            float f0[8], f1[8], f2[8], f3[8];
            unpack8(w0, f0); unpack8(w1, f1); unpack8(w2, f2); unpack8(w3, f3);
            #pragma unroll
            for (int j = 0; j < 8; ++j) {
                a0[j] = fmaf(m0, f0[j], a0[j]);
                a1[j] = fmaf(m1, f1[j], a1[j]);
                a2[j] = fmaf(m2, f2[j], a2[j]);
                a3[j] = fmaf(m3, f3[j], a3[j]);
            }
        }
    }

    float r[8];
    #pragma unroll
    for (int k = 0; k < 8; ++k) r[k] = (a0[k] + a1[k]) + (a2[k] + a3[k]);
    #pragma unroll
    for (int k = 0; k < 8; ++k) {
        r[k] += __shfl_xor(r[k], 8);
        r[k] += __shfl_xor(r[k], 16);
        r[k] += __shfl_xor(r[k], 32);
    }

    if (lane < 8) {
        float4* orow = reinterpret_cast<float4*>(out + (size_t)node * D_FEAT);
        orow[2 * ch]     = make_float4(r[0], r[1], r[2], r[3]);
        orow[2 * ch + 1] = make_float4(r[4], r[5], r[6], r[7]);
    }
}

// Fallback (f32 gather) if ws can't hold the bf16 table.
__global__ __launch_bounds__(256) void aggregate_f32_kernel(
        const float* __restrict__ feat,
        const int* __restrict__ neigh_idx,
        const int* __restrict__ offsets,
        float* __restrict__ out) {
    int node  = blockIdx.x * 4 + (threadIdx.x >> 6);
    if (node >= N_NODES) return;
    int lane  = threadIdx.x & 63;
    int sub   = lane >> 4;
    int chunk = lane & 15;
    int s = offsets[node];
    int e = offsets[node + 1];
    float4 a0 = make_float4(0.f, 0.f, 0.f, 0.f);
    float4 a1 = make_float4(0.f, 0.f, 0.f, 0.f);
    for (int base = s; base < e; base += 8) {
        int i0 = base + sub, i1 = i0 + 4;
        int c0 = (i0 < e) ? i0 : (e - 1);
        int c1 = (i1 < e) ? i1 : (e - 1);
        float m0 = (i0 < e) ? 1.f : 0.f;
        float m1 = (i1 < e) ? 1.f : 0.f;
        int n0 = neigh_idx[c0], n1 = neigh_idx[c1];
        float4 v0 = reinterpret_cast<const float4*>(feat + (size_t)n0 * D_FEAT)[chunk];
        float4 v1 = reinterpret_cast<const float4*>(feat + (size_t)n1 * D_FEAT)[chunk];
        a0.x = fmaf(m0, v0.x, a0.x); a0.y = fmaf(m0, v0.y, a0.y);
        a0.z = fmaf(m0, v0.z, a0.z); a0.w = fmaf(m0, v0.w, a0.w);
        a1.x = fmaf(m1, v1.x, a1.x); a1.y = fmaf(m1, v1.y, a1.y);
        a1.z = fmaf(m1, v1.z, a1.z); a1.w = fmaf(m1, v1.w, a1.w);
    }
    float4 acc;
    acc.x = a0.x + a1.x; acc.y = a0.y + a1.y;
    acc.z = a0.z + a1.z; acc.w = a0.w + a1.w;
    acc.x += __shfl_xor(acc.x, 16); acc.y += __shfl_xor(acc.y, 16);
    acc.z += __shfl_xor(acc.z, 16); acc.w += __shfl_xor(acc.w, 16);
    acc.x += __shfl_xor(acc.x, 32); acc.y += __shfl_xor(acc.y, 32);
    acc.z += __shfl_xor(acc.z, 32); acc.w += __shfl_xor(acc.w, 32);
    if (lane < 16) {
        reinterpret_cast<float4*>(out + (size_t)node * D_FEAT)[chunk] = acc;
    }
}

extern "C" void kernel_launch(void* const* d_in, const int* in_sizes, int n_in,
                              void* d_out, int out_size, void* d_ws, size_t ws_size,
                              hipStream_t stream) {
    const float* features  = (const float*)d_in[0];
    const int*   neigh_idx = (const int*)d_in[1];
    const int*   seg_ids   = (const int*)d_in[2];
    float*       out       = (float*)d_out;
    char*        wsb       = (char*)d_ws;
    int*         offsets   = (int*)wsb;

    bool bf16_path = (ws_size >= (size_t)OFF_WS_BYTES + BF16_WS_BYTES);
    if (bf16_path) {
        ushort* fb = (ushort*)(wsb + OFF_WS_BYTES);
        prep_kernel<<<OFFSET_BLOCKS + CONVERT_BLOCKS, 256, 0, stream>>>(
            features, seg_ids, offsets, fb);
        aggregate_bf16_kernel<<<(N_NODES + 3) / 4, 256, 0, stream>>>(
            fb, neigh_idx, offsets, out);
    } else {
        prep_kernel<<<OFFSET_BLOCKS, 256, 0, stream>>>(
            features, seg_ids, offsets, (ushort*)nullptr);
        aggregate_f32_kernel<<<(N_NODES + 3) / 4, 256, 0, stream>>>(
            features, neigh_idx, offsets, out);
    }
}

// Round 9
// 51.124 us; speedup vs baseline: 1.2103x; 1.2103x over previous
//
#include <hip/hip_runtime.h>
#include <hip/hip_bf16.h>

#define N_NODES 100000
#define N_EDGES 1600000
#define D_FEAT  64

// d_ws layout: [offsets (N_NODES+1) ints, padded to 1KB] [bf16 feature table]
#define OFF_WS_BYTES   ((((N_NODES + 1) * 4) + 1023) & ~1023)
#define BF16_WS_BYTES  ((size_t)N_NODES * D_FEAT * 2)
#define OFFSET_BLOCKS  ((N_NODES + 1 + 255) / 256)
#define CONVERT_BLOCKS 2048

// Fused prep (proven r6-r8): blocks [0, OFFSET_BLOCKS) binary-search offsets;
// blocks [OFFSET_BLOCKS, +CONVERT_BLOCKS) convert f32 -> bf16 (RNE) table.
__global__ __launch_bounds__(256) void prep_kernel(
        const float* __restrict__ feat,
        const int* __restrict__ seg_ids,
        int* __restrict__ offsets,
        ushort* __restrict__ fb) {
    int b = blockIdx.x;
    if (b < OFFSET_BLOCKS) {
        int n = b * 256 + threadIdx.x;
        if (n > N_NODES) return;
        int lo = 0, hi = N_EDGES;
        while (lo < hi) {
            int mid = (lo + hi) >> 1;
            if (seg_ids[mid] < n) lo = mid + 1; else hi = mid;
        }
        offsets[n] = lo;
    } else {
        const int total = N_NODES * D_FEAT / 4;
        int tid = (b - OFFSET_BLOCKS) * 256 + threadIdx.x;
        for (int i = tid; i < total; i += CONVERT_BLOCKS * 256) {
            float4 v = reinterpret_cast<const float4*>(feat)[i];
            uint ux = __float_as_uint(v.x), uy = __float_as_uint(v.y);
            uint uz = __float_as_uint(v.z), uw = __float_as_uint(v.w);
            ushort4 o;
            o.x = (ushort)((ux + 0x7fffu + ((ux >> 16) & 1u)) >> 16);
            o.y = (ushort)((uy + 0x7fffu + ((uy >> 16) & 1u)) >> 16);
            o.z = (ushort)((uz + 0x7fffu + ((uz >> 16) & 1u)) >> 16);
            o.w = (ushort)((uw + 0x7fffu + ((uw >> 16) & 1u)) >> 16);
            reinterpret_cast<ushort4*>(fb)[i] = o;
        }
    }
}

// Aggregate (VERBATIM round-5 body — best measured ~39us): wave-per-node.
//   - one wave-wide load stages up to 64 edge indices in registers
//     (my_idx = neigh_idx[cb + lane]); indices distributed via __shfl.
//   - sub = lane>>4 picks the edge slot (0..3), chunk = lane&15 picks the
//     8-byte bf16 chunk. 16 edges/iter, 4 uint2 gathers in flight per lane,
//     zero wasted requests for segments <= 16 (the common case).
//   - f32 accumulate, shfl_xor(16,32) reduce, lanes 0-15 store float4.
// Disjoint writes, no atomics -> deterministic across replays.
__global__ __launch_bounds__(256) void aggregate_bf16_kernel(
        const ushort* __restrict__ fb,
        const int* __restrict__ neigh_idx,
        const int* __restrict__ offsets,
        float* __restrict__ out) {
    int node  = blockIdx.x * 4 + (threadIdx.x >> 6);   // wave-uniform
    if (node >= N_NODES) return;
    int lane  = threadIdx.x & 63;
    int sub   = lane >> 4;
    int chunk = lane & 15;

    int s = offsets[node];
    int e = offsets[node + 1];

    float4 a0 = make_float4(0.f, 0.f, 0.f, 0.f);
    float4 a1 = make_float4(0.f, 0.f, 0.f, 0.f);
    float4 a2 = make_float4(0.f, 0.f, 0.f, 0.f);
    float4 a3 = make_float4(0.f, 0.f, 0.f, 0.f);

    for (int cb = s; cb < e; cb += 64) {           // 64-edge chunks (usually 1)
        int li = cb + lane;
        int ci = (li < e) ? li : (e - 1);          // loop entered => e-1 >= s
        int my_idx = neigh_idx[ci];                // 1 coalesced load / chunk
        int lim = e - cb; if (lim > 64) lim = 64;  // edges in this chunk

        for (int p = 0; p < lim; p += 16) {
            int p0 = p + sub, p1 = p0 + 4, p2 = p0 + 8, p3 = p0 + 12;
            int q0 = (p0 < lim) ? p0 : (lim - 1);
            int q1 = (p1 < lim) ? p1 : (lim - 1);
            int q2 = (p2 < lim) ? p2 : (lim - 1);
            int q3 = (p3 < lim) ? p3 : (lim - 1);
            float m0 = (p0 < lim) ? 1.f : 0.f;
            float m1 = (p1 < lim) ? 1.f : 0.f;
            float m2 = (p2 < lim) ? 1.f : 0.f;
            float m3 = (p3 < lim) ? 1.f : 0.f;
            int n0 = __shfl(my_idx, q0);
            int n1 = __shfl(my_idx, q1);
            int n2 = __shfl(my_idx, q2);
            int n3 = __shfl(my_idx, q3);
            uint2 w0 = reinterpret_cast<const uint2*>(fb + (size_t)n0 * D_FEAT)[chunk];
            uint2 w1 = reinterpret_cast<const uint2*>(fb + (size_t)n1 * D_FEAT)[chunk];
            uint2 w2 = reinterpret_cast<const uint2*>(fb + (size_t)n2 * D_FEAT)[chunk];
            uint2 w3 = reinterpret_cast<const uint2*>(fb + (size_t)n3 * D_FEAT)[chunk];
            a0.x = fmaf(m0, __uint_as_float(w0.x << 16),         a0.x);
            a0.y = fmaf(m0, __uint_as_float(w0.x & 0xFFFF0000u), a0.y);
            a0.z = fmaf(m0, __uint_as_float(w0.y << 16),         a0.z);
            a0.w = fmaf(m0, __uint_as_float(w0.y & 0xFFFF0000u), a0.w);
            a1.x = fmaf(m1, __uint_as_float(w1.x << 16),         a1.x);
            a1.y = fmaf(m1, __uint_as_float(w1.x & 0xFFFF0000u), a1.y);
            a1.z = fmaf(m1, __uint_as_float(w1.y << 16),         a1.z);
            a1.w = fmaf(m1, __uint_as_float(w1.y & 0xFFFF0000u), a1.w);
            a2.x = fmaf(m2, __uint_as_float(w2.x << 16),         a2.x);
            a2.y = fmaf(m2, __uint_as_float(w2.x & 0xFFFF0000u), a2.y);
            a2.z = fmaf(m2, __uint_as_float(w2.y << 16),         a2.z);
            a2.w = fmaf(m2, __uint_as_float(w2.y & 0xFFFF0000u), a2.w);
            a3.x = fmaf(m3, __uint_as_float(w3.x << 16),         a3.x);
            a3.y = fmaf(m3, __uint_as_float(w3.x & 0xFFFF0000u), a3.y);
            a3.z = fmaf(m3, __uint_as_float(w3.y << 16),         a3.z);
            a3.w = fmaf(m3, __uint_as_float(w3.y & 0xFFFF0000u), a3.w);
        }
    }

    float4 acc;
    acc.x = (a0.x + a1.x) + (a2.x + a3.x);
    acc.y = (a0.y + a1.y) + (a2.y + a3.y);
    acc.z = (a0.z + a1.z) + (a2.z + a3.z);
    acc.w = (a0.w + a1.w) + (a2.w + a3.w);

    acc.x += __shfl_xor(acc.x, 16);
    acc.y += __shfl_xor(acc.y, 16);
    acc.z += __shfl_xor(acc.z, 16);
    acc.w += __shfl_xor(acc.w, 16);
    acc.x += __shfl_xor(acc.x, 32);
    acc.y += __shfl_xor(acc.y, 32);
    acc.z += __shfl_xor(acc.z, 32);
    acc.w += __shfl_xor(acc.w, 32);

    if (lane < 16) {
        reinterpret_cast<float4*>(out + (size_t)node * D_FEAT)[chunk] = acc;
    }
}

// Fallback (f32 gather) if ws can't hold the bf16 table.
__global__ __launch_bounds__(256) void aggregate_f32_kernel(
        const float* __restrict__ feat,
        const int* __restrict__ neigh_idx,
        const int* __restrict__ offsets,
        float* __restrict__ out) {
    int node  = blockIdx.x * 4 + (threadIdx.x >> 6);
    if (node >= N_NODES) return;
    int lane  = threadIdx.x & 63;
    int sub   = lane >> 4;
    int chunk = lane & 15;
    int s = offsets[node];
    int e = offsets[node + 1];
    float4 a0 = make_float4(0.f, 0.f, 0.f, 0.f);
    float4 a1 = make_float4(0.f, 0.f, 0.f, 0.f);
    for (int base = s; base < e; base += 8) {
        int i0 = base + sub, i1 = i0 + 4;
        int c0 = (i0 < e) ? i0 : (e - 1);
        int c1 = (i1 < e) ? i1 : (e - 1);
        float m0 = (i0 < e) ? 1.f : 0.f;
        float m1 = (i1 < e) ? 1.f : 0.f;
        int n0 = neigh_idx[c0], n1 = neigh_idx[c1];
        float4 v0 = reinterpret_cast<const float4*>(feat + (size_t)n0 * D_FEAT)[chunk];
        float4 v1 = reinterpret_cast<const float4*>(feat + (size_t)n1 * D_FEAT)[chunk];
        a0.x = fmaf(m0, v0.x, a0.x); a0.y = fmaf(m0, v0.y, a0.y);
        a0.z = fmaf(m0, v0.z, a0.z); a0.w = fmaf(m0, v0.w, a0.w);
        a1.x = fmaf(m1, v1.x, a1.x); a1.y = fmaf(m1, v1.y, a1.y);
        a1.z = fmaf(m1, v1.z, a1.z); a1.w = fmaf(m1, v1.w, a1.w);
    }
    float4 acc;
    acc.x = a0.x + a1.x; acc.y = a0.y + a1.y;
    acc.z = a0.z + a1.z; acc.w = a0.w + a1.w;
    acc.x += __shfl_xor(acc.x, 16); acc.y += __shfl_xor(acc.y, 16);
    acc.z += __shfl_xor(acc.z, 16); acc.w += __shfl_xor(acc.w, 16);
    acc.x += __shfl_xor(acc.x, 32); acc.y += __shfl_xor(acc.y, 32);
    acc.z += __shfl_xor(acc.z, 32); acc.w += __shfl_xor(acc.w, 32);
    if (lane < 16) {
        reinterpret_cast<float4*>(out + (size_t)node * D_FEAT)[chunk] = acc;
    }
}

extern "C" void kernel_launch(void* const* d_in, const int* in_sizes, int n_in,
                              void* d_out, int out_size, void* d_ws, size_t ws_size,
                              hipStream_t stream) {
    const float* features  = (const float*)d_in[0];
    const int*   neigh_idx = (const int*)d_in[1];
    const int*   seg_ids   = (const int*)d_in[2];
    float*       out       = (float*)d_out;
    char*        wsb       = (char*)d_ws;
    int*         offsets   = (int*)wsb;

    bool bf16_path = (ws_size >= (size_t)OFF_WS_BYTES + BF16_WS_BYTES);
    if (bf16_path) {
        ushort* fb = (ushort*)(wsb + OFF_WS_BYTES);
        prep_kernel<<<OFFSET_BLOCKS + CONVERT_BLOCKS, 256, 0, stream>>>(
            features, seg_ids, offsets, fb);
        aggregate_bf16_kernel<<<(N_NODES + 3) / 4, 256, 0, stream>>>(
            fb, neigh_idx, offsets, out);
    } else {
        prep_kernel<<<OFFSET_BLOCKS, 256, 0, stream>>>(
            features, seg_ids, offsets, (ushort*)nullptr);
        aggregate_f32_kernel<<<(N_NODES + 3) / 4, 256, 0, stream>>>(
            features, neigh_idx, offsets, out);
    }
}